// Round 3
// baseline (246.590 us; speedup 1.0000x reference)
//
#include <hip/hip_runtime.h>
#include <hip/hip_bf16.h>

#define N_ROWS 8192
#define DIM 512
#define SCALE 2.659f
#define MAXLOGIT 2.659f
#define LOG2E 1.4426950408889634f
#define NCHUNK 16
#define CHUNK 512
#define BM 128
#define BN 128
#define NCLS 128

typedef __attribute__((ext_vector_type(8))) short short8;
typedef __attribute__((ext_vector_type(4))) float f32x4;

__device__ __forceinline__ unsigned short f2bf(float f) {
    unsigned int u = __float_as_uint(f);
    u += 0x7fffu + ((u >> 16) & 1u);
    return (unsigned short)(u >> 16);
}
__device__ __forceinline__ float bf2f(unsigned short s) {
    return __uint_as_float((unsigned)s << 16);
}

// ---------------------------------------------------------------- normalize
// Also zero-initializes rs/cs accumulators (64 KB) and out[0].
__global__ __launch_bounds__(256) void norm_cast_kernel(
    const float* __restrict__ text, const float* __restrict__ image,
    unsigned short* __restrict__ imgn, unsigned short* __restrict__ txtn,
    float4* __restrict__ zbase, float* __restrict__ out)
{
    if (blockIdx.x < 16) {
        zbase[blockIdx.x * 256 + threadIdx.x] = make_float4(0.f, 0.f, 0.f, 0.f);
        if (blockIdx.x == 0 && threadIdx.x == 0) out[0] = 0.f;
    }
    int row  = blockIdx.x * 4 + (threadIdx.x >> 6);
    int lane = threadIdx.x & 63;
    const float* src;
    unsigned short* dst;
    if (row < N_ROWS) { src = image + (size_t)row * DIM; dst = imgn + (size_t)row * DIM; }
    else { int r = row - N_ROWS; src = text + (size_t)r * DIM; dst = txtn + (size_t)r * DIM; }
    const float4* s4 = (const float4*)src + lane * 2;
    float4 a = s4[0], b = s4[1];
    float ss = a.x*a.x + a.y*a.y + a.z*a.z + a.w*a.w
             + b.x*b.x + b.y*b.y + b.z*b.z + b.w*b.w;
    #pragma unroll
    for (int m = 1; m < 64; m <<= 1) ss += __shfl_xor(ss, m, 64);
    float sc = 1.0f / fmaxf(sqrtf(ss), 1e-12f);
    uint4 o;
    o.x = (unsigned)f2bf(a.x*sc) | ((unsigned)f2bf(a.y*sc) << 16);
    o.y = (unsigned)f2bf(a.z*sc) | ((unsigned)f2bf(a.w*sc) << 16);
    o.z = (unsigned)f2bf(b.x*sc) | ((unsigned)f2bf(b.y*sc) << 16);
    o.w = (unsigned)f2bf(b.z*sc) | ((unsigned)f2bf(b.w*sc) << 16);
    *((uint4*)dst + lane) = o;
}

// ---------------------------------------------------------------- class sums
// c_txt[l] = sum of txtn rows with label l (f32), c_img[l] same over imgn,
// cnt[l] = class size. One block per (class, matrix).
__global__ __launch_bounds__(256) void class_sum_kernel(
    const unsigned short* __restrict__ imgn, const unsigned short* __restrict__ txtn,
    const int* __restrict__ labels,
    float* __restrict__ c_txt, float* __restrict__ c_img, int* __restrict__ cnt)
{
    __shared__ int list[256];
    __shared__ int lcount;
    int cls = blockIdx.x & (NCLS - 1);
    int mat = blockIdx.x >> 7;                 // 0: txt sums, 1: img sums
    const unsigned* src = (const unsigned*)(mat ? imgn : txtn);
    float* dst = mat ? c_img : c_txt;
    int tid = threadIdx.x;
    float a0 = 0.f, a1 = 0.f;
    int total = 0;
    for (int base = 0; base < N_ROWS; base += 256) {
        if (tid == 0) lcount = 0;
        __syncthreads();
        int lb = labels[base + tid];
        if (lb == cls) { int s = atomicAdd(&lcount, 1); list[s] = base + tid; }
        __syncthreads();
        int m = lcount;
        total += m;
        int r = 0;
        for (; r + 4 <= m; r += 4) {           // 4 independent loads in flight
            unsigned u0 = src[(size_t)list[r]   * (DIM/2) + tid];
            unsigned u1 = src[(size_t)list[r+1] * (DIM/2) + tid];
            unsigned u2 = src[(size_t)list[r+2] * (DIM/2) + tid];
            unsigned u3 = src[(size_t)list[r+3] * (DIM/2) + tid];
            a0 += __uint_as_float((u0 & 0xffffu) << 16) + __uint_as_float((u1 & 0xffffu) << 16)
                + __uint_as_float((u2 & 0xffffu) << 16) + __uint_as_float((u3 & 0xffffu) << 16);
            a1 += __uint_as_float(u0 & 0xffff0000u) + __uint_as_float(u1 & 0xffff0000u)
                + __uint_as_float(u2 & 0xffff0000u) + __uint_as_float(u3 & 0xffff0000u);
        }
        for (; r < m; ++r) {
            unsigned u = src[(size_t)list[r] * (DIM/2) + tid];
            a0 += __uint_as_float((u & 0xffffu) << 16);
            a1 += __uint_as_float(u & 0xffff0000u);
        }
        __syncthreads();
    }
    dst[(size_t)cls * DIM + tid*2]     = a0;
    dst[(size_t)cls * DIM + tid*2 + 1] = a1;
    if (mat == 0 && tid == 0) cnt[cls] = total;
}

// ---------------------------------------------------------------- fused GEMM
// S = scale*(img @ txt^T) once; epilogue accumulates ONLY exp sums (row via
// registers, col via LDS slots). The d-terms are handled algebraically by
// class sums (see loss_final_kernel), so no labels/compares here.
#define ASYNC16(gp, lp) \
  __builtin_amdgcn_global_load_lds((const __attribute__((address_space(1))) void*)(gp), \
                                   (__attribute__((address_space(3))) void*)(lp), 16, 0, 0)

__global__ __launch_bounds__(256, 4) void gemm_fused_kernel(
    const unsigned short* __restrict__ imgn, const unsigned short* __restrict__ txtn,
    float* __restrict__ rs, float* __restrict__ cs)
{
    __shared__ unsigned short Ald[BM * 32];
    __shared__ unsigned short Bld[BN * 32];
    __shared__ float red[2][BM];
    __shared__ float colb[2][CHUNK];      // [wr][col-in-chunk], written once each

    int bid    = blockIdx.x;
    int rowblk = bid & 63;
    int chunk  = bid >> 6;
    const unsigned short* A = imgn;
    const unsigned short* B = txtn;
    int rowBase  = rowblk * BM;
    int colBase0 = chunk * CHUNK;

    int tid  = threadIdx.x;
    int lane = tid & 63;
    int w    = tid >> 6;
    int wr   = w >> 1, wc = w & 1;
    int q    = lane >> 4;
    int lm   = lane & 15;

    float s_acc[16];
    #pragma unroll
    for (int i = 0; i < 16; ++i) s_acc[i] = 0.f;

    int srow  = lane >> 2;        // staging: row within 16-row group
    int spart = (lane & 3) * 8;   // staging: k offset (elems)

    const float C1 = SCALE * LOG2E;
    const float C2 = -MAXLOGIT * LOG2E;

    for (int tile = 0; tile < CHUNK / BN; ++tile) {
        int colBase = colBase0 + tile * BN;
        f32x4 acc[4][4];
        #pragma unroll
        for (int mi = 0; mi < 4; ++mi)
          #pragma unroll
          for (int ni = 0; ni < 4; ++ni)
            acc[mi][ni] = (f32x4){0.f, 0.f, 0.f, 0.f};

        for (int kt = 0; kt < DIM / 32; ++kt) {
            int k0 = kt * 32;
            __syncthreads();   // all waves done reading LDS before re-stage
            #pragma unroll
            for (int i = 0; i < 2; ++i) {
                int rlocal = i*64 + w*16 + srow;
                ASYNC16(A + (size_t)(rowBase + rlocal) * DIM + k0 + spart,
                        Ald + (i*64 + w*16) * 32);
                ASYNC16(B + (size_t)(colBase + rlocal) * DIM + k0 + spart,
                        Bld + (i*64 + w*16) * 32);
            }
            __syncthreads();   // drains vmcnt(0): staging complete

            short8 af[4], bf[4];
            #pragma unroll
            for (int mi = 0; mi < 4; ++mi)
                af[mi] = *(const short8*)(Ald + (wr*64 + mi*16 + lm)*32 + q*8);
            #pragma unroll
            for (int ni = 0; ni < 4; ++ni)
                bf[ni] = *(const short8*)(Bld + (wc*64 + ni*16 + lm)*32 + q*8);
            #pragma unroll
            for (int mi = 0; mi < 4; ++mi)
              #pragma unroll
              for (int ni = 0; ni < 4; ++ni)
                acc[mi][ni] = __builtin_amdgcn_mfma_f32_16x16x32_bf16(
                                  af[mi], bf[ni], acc[mi][ni], 0, 0, 0);
        }

        // epilogue: exp-sum only; one exp serves both loss directions.
        #pragma unroll
        for (int ni = 0; ni < 4; ++ni) {
            float csum = 0.f;
            #pragma unroll
            for (int mi = 0; mi < 4; ++mi) {
              #pragma unroll
              for (int r = 0; r < 4; ++r) {
                float e = __builtin_amdgcn_exp2f(fmaf(acc[mi][ni][r], C1, C2));
                s_acc[mi*4 + r] += e;
                csum += e;
              }
            }
            csum += __shfl_xor(csum, 16, 64);
            csum += __shfl_xor(csum, 32, 64);
            if (q == 0)
                colb[wr][tile*BN + wc*64 + ni*16 + lm] = csum;
        }
    }

    // row stats: reduce across the 16 column-lanes (low 4 lane bits)
    #pragma unroll
    for (int idx = 0; idx < 16; ++idx) {
        float s = s_acc[idx];
        #pragma unroll
        for (int m = 1; m < 16; m <<= 1) s += __shfl_xor(s, m, 64);
        s_acc[idx] = s;
    }
    if (lm == 0) {
        #pragma unroll
        for (int idx = 0; idx < 16; ++idx) {
            int rl = wr*64 + (idx>>2)*16 + q*4 + (idx&3);
            red[wc][rl] = s_acc[idx];
        }
    }
    __syncthreads();
    if (tid < BM)
        unsafeAtomicAdd(&rs[rowBase + tid], red[0][tid] + red[1][tid]);
    for (int c = tid; c < CHUNK; c += 256)
        unsafeAtomicAdd(&cs[colBase0 + c], colb[0][c] + colb[1][c]);
}

// ---------------------------------------------------------------- final loss
// d_row[i] = scale*<a_i, c_txt[lab_i]>  (or <a_i,b_i> if lab_i == -1)
// d_col[i] = scale*<b_i, c_img[lab_i]>  (or same self-dot)
// loss contribution = (M+log rs[i]) - d_row/sT + (M+log cs[i]) - d_col/sT
__global__ __launch_bounds__(256) void loss_final_kernel(
    const unsigned short* __restrict__ imgn, const unsigned short* __restrict__ txtn,
    const int* __restrict__ labels, const float* __restrict__ rs,
    const float* __restrict__ cs, const float* __restrict__ c_txt,
    const float* __restrict__ c_img, const int* __restrict__ cnt,
    float* __restrict__ out)
{
    __shared__ float wsum[4];
    int tid = threadIdx.x, lane = tid & 63, w = tid >> 6;
    int wid = blockIdx.x * 4 + w;          // 0..2047
    float local = 0.f;
    for (int k = 0; k < 4; ++k) {
        int i   = wid + 2048 * k;
        int lab = labels[i];
        short8 av = *((const short8*)(imgn + (size_t)i * DIM) + lane);
        short8 bv = *((const short8*)(txtn + (size_t)i * DIM) + lane);
        float d1 = 0.f, d2 = 0.f;
        if (lab >= 0) {
            const float4* xp = (const float4*)(c_txt + (size_t)lab * DIM) + lane * 2;
            const float4* yp = (const float4*)(c_img + (size_t)lab * DIM) + lane * 2;
            float4 x0 = xp[0], x1 = xp[1], y0 = yp[0], y1 = yp[1];
            float xa[8] = {x0.x, x0.y, x0.z, x0.w, x1.x, x1.y, x1.z, x1.w};
            float ya[8] = {y0.x, y0.y, y0.z, y0.w, y1.x, y1.y, y1.z, y1.w};
            #pragma unroll
            for (int e = 0; e < 8; ++e) {
                d1 = fmaf(bf2f((unsigned short)av[e]), xa[e], d1);
                d2 = fmaf(bf2f((unsigned short)bv[e]), ya[e], d2);
            }
        } else {
            #pragma unroll
            for (int e = 0; e < 8; ++e)
                d1 = fmaf(bf2f((unsigned short)av[e]), bf2f((unsigned short)bv[e]), d1);
            d2 = d1;                        // self-dot is shared
        }
        #pragma unroll
        for (int m = 1; m < 64; m <<= 1) {
            d1 += __shfl_xor(d1, m, 64);
            d2 += __shfl_xor(d2, m, 64);
        }
        if (lane == 0) {
            float sT = (lab < 0) ? 1.0f : (float)cnt[lab];
            local += (MAXLOGIT + logf(rs[i])) - SCALE * d1 / sT
                   + (MAXLOGIT + logf(cs[i])) - SCALE * d2 / sT;
        }
    }
    if (lane == 0) wsum[w] = local;
    __syncthreads();
    if (tid == 0)
        unsafeAtomicAdd(out, (wsum[0] + wsum[1] + wsum[2] + wsum[3])
                             * (1.0f / (2 * N_ROWS)));
}

// ---------------------------------------------------------------- launch
extern "C" void kernel_launch(void* const* d_in, const int* in_sizes, int n_in,
                              void* d_out, int out_size, void* d_ws, size_t ws_size,
                              hipStream_t stream)
{
    const float* text   = (const float*)d_in[0];
    const float* image  = (const float*)d_in[1];
    const int*   labels = (const int*)d_in[2];

    unsigned short* imgn = (unsigned short*)d_ws;
    unsigned short* txtn = imgn + (size_t)N_ROWS * DIM;
    char* p = (char*)d_ws + 2 * (size_t)N_ROWS * DIM * sizeof(unsigned short);
    float* rs    = (float*)p;                       // 8192 f32
    float* cs    = rs + N_ROWS;                     // 8192 f32
    float* c_txt = cs + N_ROWS;                     // 128*512 f32
    float* c_img = c_txt + (size_t)NCLS * DIM;      // 128*512 f32
    int*   cnt   = (int*)(c_img + (size_t)NCLS * DIM);
    float* out = (float*)d_out;

    hipLaunchKernelGGL(norm_cast_kernel, dim3(2 * N_ROWS / 4), dim3(256), 0, stream,
                       text, image, imgn, txtn, (float4*)rs, out);
    hipLaunchKernelGGL(gemm_fused_kernel, dim3(64 * NCHUNK), dim3(256), 0, stream,
                       imgn, txtn, rs, cs);
    hipLaunchKernelGGL(class_sum_kernel, dim3(2 * NCLS), dim3(256), 0, stream,
                       imgn, txtn, labels, c_txt, c_img, cnt);
    hipLaunchKernelGGL(loss_final_kernel, dim3(512), dim3(256), 0, stream,
                       imgn, txtn, labels, rs, cs, c_txt, c_img, cnt, out);
}

// Round 4
// 216.210 us; speedup vs baseline: 1.1405x; 1.1405x over previous
//
#include <hip/hip_runtime.h>
#include <hip/hip_bf16.h>

#define N_ROWS 8192
#define DIM 512
#define SCALE 2.659f
#define MAXLOGIT 2.659f
#define LOG2E 1.4426950408889634f
#define NCHUNK 16
#define CHUNK 512
#define BM 128
#define BN 128
#define NCLS 128

typedef __attribute__((ext_vector_type(8))) short short8;
typedef __attribute__((ext_vector_type(4))) float f32x4;

__device__ __forceinline__ unsigned short f2bf(float f) {
    unsigned int u = __float_as_uint(f);
    u += 0x7fffu + ((u >> 16) & 1u);
    return (unsigned short)(u >> 16);
}
__device__ __forceinline__ float bf2f(unsigned short s) {
    return __uint_as_float((unsigned)s << 16);
}

// ---------------------------------------------------------------- normalize
// One wave handles image row i AND text row i: computes both norms, writes
// both bf16 rows, and emits the self-dot <a_i,b_i> (needed when label==-1).
// Also zero-initializes rs/cs accumulators (64 KB) and out[0].
__global__ __launch_bounds__(256) void norm_cast_kernel(
    const float* __restrict__ text, const float* __restrict__ image,
    const int* __restrict__ labels,
    unsigned short* __restrict__ imgn, unsigned short* __restrict__ txtn,
    float4* __restrict__ zbase, float* __restrict__ sd, float* __restrict__ out)
{
    if (blockIdx.x < 16) {
        zbase[blockIdx.x * 256 + threadIdx.x] = make_float4(0.f, 0.f, 0.f, 0.f);
        if (blockIdx.x == 0 && threadIdx.x == 0) out[0] = 0.f;
    }
    int row  = blockIdx.x * 4 + (threadIdx.x >> 6);
    int lane = threadIdx.x & 63;
    const float4* si = (const float4*)(image + (size_t)row * DIM) + lane * 2;
    const float4* st = (const float4*)(text  + (size_t)row * DIM) + lane * 2;
    float4 a = si[0], b = si[1], c = st[0], d = st[1];
    float ssa = a.x*a.x + a.y*a.y + a.z*a.z + a.w*a.w
              + b.x*b.x + b.y*b.y + b.z*b.z + b.w*b.w;
    float sst = c.x*c.x + c.y*c.y + c.z*c.z + c.w*c.w
              + d.x*d.x + d.y*d.y + d.z*d.z + d.w*d.w;
    float sab = a.x*c.x + a.y*c.y + a.z*c.z + a.w*c.w
              + b.x*d.x + b.y*d.y + b.z*d.z + b.w*d.w;
    #pragma unroll
    for (int m = 1; m < 64; m <<= 1) {
        ssa += __shfl_xor(ssa, m, 64);
        sst += __shfl_xor(sst, m, 64);
        sab += __shfl_xor(sab, m, 64);
    }
    float sca = 1.0f / fmaxf(sqrtf(ssa), 1e-12f);
    float sct = 1.0f / fmaxf(sqrtf(sst), 1e-12f);
    uint4 oi, ot;
    oi.x = (unsigned)f2bf(a.x*sca) | ((unsigned)f2bf(a.y*sca) << 16);
    oi.y = (unsigned)f2bf(a.z*sca) | ((unsigned)f2bf(a.w*sca) << 16);
    oi.z = (unsigned)f2bf(b.x*sca) | ((unsigned)f2bf(b.y*sca) << 16);
    oi.w = (unsigned)f2bf(b.z*sca) | ((unsigned)f2bf(b.w*sca) << 16);
    ot.x = (unsigned)f2bf(c.x*sct) | ((unsigned)f2bf(c.y*sct) << 16);
    ot.y = (unsigned)f2bf(c.z*sct) | ((unsigned)f2bf(c.w*sct) << 16);
    ot.z = (unsigned)f2bf(d.x*sct) | ((unsigned)f2bf(d.y*sct) << 16);
    ot.w = (unsigned)f2bf(d.z*sct) | ((unsigned)f2bf(d.w*sct) << 16);
    *((uint4*)(imgn + (size_t)row * DIM) + lane) = oi;
    *((uint4*)(txtn + (size_t)row * DIM) + lane) = ot;
    if (lane == 0)
        sd[row] = (labels[row] < 0) ? sab * sca * sct : 0.0f;
}

// ---------------------------------------------------------------- class sums
// c_txt[l] = sum of txtn rows with label l (f32), c_img[l] same over imgn,
// cnt[l] = class size. One block per (class, matrix).
__global__ __launch_bounds__(256) void class_sum_kernel(
    const unsigned short* __restrict__ imgn, const unsigned short* __restrict__ txtn,
    const int* __restrict__ labels,
    float* __restrict__ c_txt, float* __restrict__ c_img, int* __restrict__ cnt)
{
    __shared__ int list[256];
    __shared__ int lcount;
    int cls = blockIdx.x & (NCLS - 1);
    int mat = blockIdx.x >> 7;                 // 0: txt sums, 1: img sums
    const unsigned* src = (const unsigned*)(mat ? imgn : txtn);
    float* dst = mat ? c_img : c_txt;
    int tid = threadIdx.x;
    float a0 = 0.f, a1 = 0.f;
    int total = 0;
    for (int base = 0; base < N_ROWS; base += 256) {
        if (tid == 0) lcount = 0;
        __syncthreads();
        int lb = labels[base + tid];
        if (lb == cls) { int s = atomicAdd(&lcount, 1); list[s] = base + tid; }
        __syncthreads();
        int m = lcount;
        total += m;
        int r = 0;
        for (; r + 4 <= m; r += 4) {           // 4 independent loads in flight
            unsigned u0 = src[(size_t)list[r]   * (DIM/2) + tid];
            unsigned u1 = src[(size_t)list[r+1] * (DIM/2) + tid];
            unsigned u2 = src[(size_t)list[r+2] * (DIM/2) + tid];
            unsigned u3 = src[(size_t)list[r+3] * (DIM/2) + tid];
            a0 += __uint_as_float((u0 & 0xffffu) << 16) + __uint_as_float((u1 & 0xffffu) << 16)
                + __uint_as_float((u2 & 0xffffu) << 16) + __uint_as_float((u3 & 0xffffu) << 16);
            a1 += __uint_as_float(u0 & 0xffff0000u) + __uint_as_float(u1 & 0xffff0000u)
                + __uint_as_float(u2 & 0xffff0000u) + __uint_as_float(u3 & 0xffff0000u);
        }
        for (; r < m; ++r) {
            unsigned u = src[(size_t)list[r] * (DIM/2) + tid];
            a0 += __uint_as_float((u & 0xffffu) << 16);
            a1 += __uint_as_float(u & 0xffff0000u);
        }
        __syncthreads();
    }
    dst[(size_t)cls * DIM + tid*2]     = a0;
    dst[(size_t)cls * DIM + tid*2 + 1] = a1;
    if (mat == 0 && tid == 0) cnt[cls] = total;
}

// ---------------------------------------------------------------- fused GEMM
// S = scale*(img @ txt^T) once; epilogue accumulates ONLY exp sums (row via
// registers, col via LDS slots). d-terms handled algebraically elsewhere.
#define ASYNC16(gp, lp) \
  __builtin_amdgcn_global_load_lds((const __attribute__((address_space(1))) void*)(gp), \
                                   (__attribute__((address_space(3))) void*)(lp), 16, 0, 0)

__global__ __launch_bounds__(256, 2) void gemm_fused_kernel(
    const unsigned short* __restrict__ imgn, const unsigned short* __restrict__ txtn,
    float* __restrict__ rs, float* __restrict__ cs)
{
    __shared__ unsigned short Ald[BM * 32];
    __shared__ unsigned short Bld[BN * 32];
    __shared__ float red[2][BM];
    __shared__ float colb[2][CHUNK];      // [wr][col-in-chunk], written once each

    // XCD-aware bijective swizzle (nwg=1024, 8 XCDs): XCD x gets bids
    // [x*128, x*128+128) = chunks {2x, 2x+1} over all rowblks -> per-XCD
    // B working set = 1 MB (L2-resident).
    int hwbid = blockIdx.x;
    int bid   = (hwbid & 7) * 128 + (hwbid >> 3);
    int rowblk = bid & 63;
    int chunk  = bid >> 6;
    const unsigned short* A = imgn;
    const unsigned short* B = txtn;
    int rowBase  = rowblk * BM;
    int colBase0 = chunk * CHUNK;

    int tid  = threadIdx.x;
    int lane = tid & 63;
    int w    = tid >> 6;
    int wr   = w >> 1, wc = w & 1;
    int q    = lane >> 4;
    int lm   = lane & 15;

    float s_acc[16];
    #pragma unroll
    for (int i = 0; i < 16; ++i) s_acc[i] = 0.f;

    int srow  = lane >> 2;        // staging: row within 16-row group
    int spart = (lane & 3) * 8;   // staging: k offset (elems)

    const float C1 = SCALE * LOG2E;
    const float C2 = -MAXLOGIT * LOG2E;

    for (int tile = 0; tile < CHUNK / BN; ++tile) {
        int colBase = colBase0 + tile * BN;
        f32x4 acc[4][4];
        #pragma unroll
        for (int mi = 0; mi < 4; ++mi)
          #pragma unroll
          for (int ni = 0; ni < 4; ++ni)
            acc[mi][ni] = (f32x4){0.f, 0.f, 0.f, 0.f};

        for (int kt = 0; kt < DIM / 32; ++kt) {
            int k0 = kt * 32;
            __syncthreads();   // all waves done reading LDS before re-stage
            #pragma unroll
            for (int i = 0; i < 2; ++i) {
                int rlocal = i*64 + w*16 + srow;
                ASYNC16(A + (size_t)(rowBase + rlocal) * DIM + k0 + spart,
                        Ald + (i*64 + w*16) * 32);
                ASYNC16(B + (size_t)(colBase + rlocal) * DIM + k0 + spart,
                        Bld + (i*64 + w*16) * 32);
            }
            __syncthreads();   // drains vmcnt(0): staging complete

            short8 af[4], bf[4];
            #pragma unroll
            for (int mi = 0; mi < 4; ++mi)
                af[mi] = *(const short8*)(Ald + (wr*64 + mi*16 + lm)*32 + q*8);
            #pragma unroll
            for (int ni = 0; ni < 4; ++ni)
                bf[ni] = *(const short8*)(Bld + (wc*64 + ni*16 + lm)*32 + q*8);
            #pragma unroll
            for (int mi = 0; mi < 4; ++mi)
              #pragma unroll
              for (int ni = 0; ni < 4; ++ni)
                acc[mi][ni] = __builtin_amdgcn_mfma_f32_16x16x32_bf16(
                                  af[mi], bf[ni], acc[mi][ni], 0, 0, 0);
        }

        // epilogue: exp-sum only; one exp serves both loss directions.
        #pragma unroll
        for (int ni = 0; ni < 4; ++ni) {
            float csum = 0.f;
            #pragma unroll
            for (int mi = 0; mi < 4; ++mi) {
              #pragma unroll
              for (int r = 0; r < 4; ++r) {
                float e = __builtin_amdgcn_exp2f(fmaf(acc[mi][ni][r], C1, C2));
                s_acc[mi*4 + r] += e;
                csum += e;
              }
            }
            csum += __shfl_xor(csum, 16, 64);
            csum += __shfl_xor(csum, 32, 64);
            if (q == 0)
                colb[wr][tile*BN + wc*64 + ni*16 + lm] = csum;
        }
    }

    // row stats: reduce across the 16 column-lanes (low 4 lane bits)
    #pragma unroll
    for (int idx = 0; idx < 16; ++idx) {
        float s = s_acc[idx];
        #pragma unroll
        for (int m = 1; m < 16; m <<= 1) s += __shfl_xor(s, m, 64);
        s_acc[idx] = s;
    }
    if (lm == 0) {
        #pragma unroll
        for (int idx = 0; idx < 16; ++idx) {
            int rl = wr*64 + (idx>>2)*16 + q*4 + (idx&3);
            red[wc][rl] = s_acc[idx];
        }
    }
    __syncthreads();
    if (tid < BM)
        unsafeAtomicAdd(&rs[rowBase + tid], red[0][tid] + red[1][tid]);
    for (int c = tid; c < CHUNK; c += 256)
        unsafeAtomicAdd(&cs[colBase0 + c], colb[0][c] + colb[1][c]);
}

// ---------------------------------------------------------------- final loss
// loss*2N = Sum_i (M + log rs_i) + Sum_i (M + log cs_i)
//           - 2*scale*[ Sum_l <c_img[l],c_txt[l]>/cnt_l + Sum_{lab=-1} <a_i,b_i> ]
// (row- and column-direction d-terms are equal by symmetry of the target.)
__global__ __launch_bounds__(256) void loss_tail_kernel(
    const float* __restrict__ rs, const float* __restrict__ cs,
    const float* __restrict__ sd, const float* __restrict__ c_txt,
    const float* __restrict__ c_img, const int* __restrict__ cnt,
    float* __restrict__ out)
{
    __shared__ float wsum[4];
    int tid = threadIdx.x, lane = tid & 63, w = tid >> 6;
    int gidx = blockIdx.x * 256 + tid;           // 0..16383
    float local;
    if (gidx < N_ROWS)
        local = (MAXLOGIT + logf(rs[gidx])) - 2.0f * SCALE * sd[gidx];
    else
        local = MAXLOGIT + logf(cs[gidx - N_ROWS]);

    // class-dot portion: 2 classes per block, 4 dims per thread
    int cls = blockIdx.x * 2 + (tid >> 7);       // 0..127
    int e0  = (tid & 127) * 4;
    int n   = cnt[cls];
    if (n > 0) {
        float4 x = *(const float4*)(c_txt + (size_t)cls * DIM + e0);
        float4 y = *(const float4*)(c_img + (size_t)cls * DIM + e0);
        float dotp = x.x*y.x + x.y*y.y + x.z*y.z + x.w*y.w;
        local -= 2.0f * SCALE * dotp / (float)n;
    }

    #pragma unroll
    for (int m = 1; m < 64; m <<= 1) local += __shfl_xor(local, m, 64);
    if (lane == 0) wsum[w] = local;
    __syncthreads();
    if (tid == 0)
        unsafeAtomicAdd(out, (wsum[0] + wsum[1] + wsum[2] + wsum[3])
                             * (1.0f / (2 * N_ROWS)));
}

// ---------------------------------------------------------------- launch
extern "C" void kernel_launch(void* const* d_in, const int* in_sizes, int n_in,
                              void* d_out, int out_size, void* d_ws, size_t ws_size,
                              hipStream_t stream)
{
    const float* text   = (const float*)d_in[0];
    const float* image  = (const float*)d_in[1];
    const int*   labels = (const int*)d_in[2];

    unsigned short* imgn = (unsigned short*)d_ws;
    unsigned short* txtn = imgn + (size_t)N_ROWS * DIM;
    char* p = (char*)d_ws + 2 * (size_t)N_ROWS * DIM * sizeof(unsigned short);
    float* rs    = (float*)p;                       // 8192 f32 (zeroed)
    float* cs    = rs + N_ROWS;                     // 8192 f32 (zeroed)
    float* sd    = cs + N_ROWS;                     // 8192 f32 (fully written)
    float* c_txt = sd + N_ROWS;                     // 128*512 f32
    float* c_img = c_txt + (size_t)NCLS * DIM;      // 128*512 f32
    int*   cnt   = (int*)(c_img + (size_t)NCLS * DIM);
    float* out = (float*)d_out;

    hipLaunchKernelGGL(norm_cast_kernel, dim3(N_ROWS / 4), dim3(256), 0, stream,
                       text, image, labels, imgn, txtn, (float4*)rs, sd, out);
    hipLaunchKernelGGL(gemm_fused_kernel, dim3(64 * NCHUNK), dim3(256), 0, stream,
                       imgn, txtn, rs, cs);
    hipLaunchKernelGGL(class_sum_kernel, dim3(2 * NCLS), dim3(256), 0, stream,
                       imgn, txtn, labels, c_txt, c_img, cnt);
    hipLaunchKernelGGL(loss_tail_kernel, dim3(64), dim3(256), 0, stream,
                       rs, cs, sd, c_txt, c_img, cnt, out);
}

// Round 5
// 193.871 us; speedup vs baseline: 1.2719x; 1.1152x over previous
//
#include <hip/hip_runtime.h>
#include <hip/hip_bf16.h>

#define N_ROWS 8192
#define DIM 512
#define SCALE 2.659f
#define MAXLOGIT 2.659f
#define LOG2E 1.4426950408889634f
#define NCHUNK 16
#define CHUNK 512
#define BM 128
#define BN 128
#define NCLS 128

typedef __attribute__((ext_vector_type(8))) short short8;
typedef __attribute__((ext_vector_type(4))) float f32x4;

__device__ __forceinline__ unsigned short f2bf(float f) {
    unsigned int u = __float_as_uint(f);
    u += 0x7fffu + ((u >> 16) & 1u);
    return (unsigned short)(u >> 16);
}
__device__ __forceinline__ float bf2f(unsigned short s) {
    return __uint_as_float((unsigned)s << 16);
}

// ---------------------------------------------------------------- normalize
// One wave handles image row i AND text row i: computes both norms, writes
// both bf16 rows, and emits the self-dot <a_i,b_i> (needed when label==-1).
// Also zero-initializes rs/cs accumulators (64 KB) and out[0].
__global__ __launch_bounds__(256) void norm_cast_kernel(
    const float* __restrict__ text, const float* __restrict__ image,
    const int* __restrict__ labels,
    unsigned short* __restrict__ imgn, unsigned short* __restrict__ txtn,
    float4* __restrict__ zbase, float* __restrict__ sd, float* __restrict__ out)
{
    if (blockIdx.x < 16) {
        zbase[blockIdx.x * 256 + threadIdx.x] = make_float4(0.f, 0.f, 0.f, 0.f);
        if (blockIdx.x == 0 && threadIdx.x == 0) out[0] = 0.f;
    }
    int row  = blockIdx.x * 4 + (threadIdx.x >> 6);
    int lane = threadIdx.x & 63;
    const float4* si = (const float4*)(image + (size_t)row * DIM) + lane * 2;
    const float4* st = (const float4*)(text  + (size_t)row * DIM) + lane * 2;
    float4 a = si[0], b = si[1], c = st[0], d = st[1];
    float ssa = a.x*a.x + a.y*a.y + a.z*a.z + a.w*a.w
              + b.x*b.x + b.y*b.y + b.z*b.z + b.w*b.w;
    float sst = c.x*c.x + c.y*c.y + c.z*c.z + c.w*c.w
              + d.x*d.x + d.y*d.y + d.z*d.z + d.w*d.w;
    float sab = a.x*c.x + a.y*c.y + a.z*c.z + a.w*c.w
              + b.x*d.x + b.y*d.y + b.z*d.z + b.w*d.w;
    #pragma unroll
    for (int m = 1; m < 64; m <<= 1) {
        ssa += __shfl_xor(ssa, m, 64);
        sst += __shfl_xor(sst, m, 64);
        sab += __shfl_xor(sab, m, 64);
    }
    float sca = 1.0f / fmaxf(sqrtf(ssa), 1e-12f);
    float sct = 1.0f / fmaxf(sqrtf(sst), 1e-12f);
    uint4 oi, ot;
    oi.x = (unsigned)f2bf(a.x*sca) | ((unsigned)f2bf(a.y*sca) << 16);
    oi.y = (unsigned)f2bf(a.z*sca) | ((unsigned)f2bf(a.w*sca) << 16);
    oi.z = (unsigned)f2bf(b.x*sca) | ((unsigned)f2bf(b.y*sca) << 16);
    oi.w = (unsigned)f2bf(b.z*sca) | ((unsigned)f2bf(b.w*sca) << 16);
    ot.x = (unsigned)f2bf(c.x*sct) | ((unsigned)f2bf(c.y*sct) << 16);
    ot.y = (unsigned)f2bf(c.z*sct) | ((unsigned)f2bf(c.w*sct) << 16);
    ot.z = (unsigned)f2bf(d.x*sct) | ((unsigned)f2bf(d.y*sct) << 16);
    ot.w = (unsigned)f2bf(d.z*sct) | ((unsigned)f2bf(d.w*sct) << 16);
    *((uint4*)(imgn + (size_t)row * DIM) + lane) = oi;
    *((uint4*)(txtn + (size_t)row * DIM) + lane) = ot;
    if (lane == 0)
        sd[row] = (labels[row] < 0) ? sab * sca * sct : 0.0f;
}

// ---------------------------------------------------------------- class sums
// One-pass list build (no per-batch barriers), then a 4-deep pipelined gather
// over the ~74 rows of this class.
__global__ __launch_bounds__(256) void class_sum_kernel(
    const unsigned short* __restrict__ imgn, const unsigned short* __restrict__ txtn,
    const int* __restrict__ labels,
    float* __restrict__ c_txt, float* __restrict__ c_img, int* __restrict__ cnt)
{
    __shared__ int list[512];
    __shared__ int lcount;
    int cls = blockIdx.x & (NCLS - 1);
    int mat = blockIdx.x >> 7;                 // 0: txt sums, 1: img sums
    const unsigned* src = (const unsigned*)(mat ? imgn : txtn);
    float* dst = mat ? c_img : c_txt;
    int tid = threadIdx.x;
    if (tid == 0) lcount = 0;
    __syncthreads();
    #pragma unroll
    for (int base = 0; base < N_ROWS; base += 256) {
        int lb = labels[base + tid];
        if (lb == cls) { int s = atomicAdd(&lcount, 1); list[s & 511] = base + tid; }
    }
    __syncthreads();
    int m = lcount;
    float a0 = 0.f, a1 = 0.f;
    int r = 0;
    for (; r + 4 <= m; r += 4) {               // 4 independent loads in flight
        unsigned u0 = src[(size_t)list[r]   * (DIM/2) + tid];
        unsigned u1 = src[(size_t)list[r+1] * (DIM/2) + tid];
        unsigned u2 = src[(size_t)list[r+2] * (DIM/2) + tid];
        unsigned u3 = src[(size_t)list[r+3] * (DIM/2) + tid];
        a0 += __uint_as_float((u0 & 0xffffu) << 16) + __uint_as_float((u1 & 0xffffu) << 16)
            + __uint_as_float((u2 & 0xffffu) << 16) + __uint_as_float((u3 & 0xffffu) << 16);
        a1 += __uint_as_float(u0 & 0xffff0000u) + __uint_as_float(u1 & 0xffff0000u)
            + __uint_as_float(u2 & 0xffff0000u) + __uint_as_float(u3 & 0xffff0000u);
    }
    for (; r < m; ++r) {
        unsigned u = src[(size_t)list[r] * (DIM/2) + tid];
        a0 += __uint_as_float((u & 0xffffu) << 16);
        a1 += __uint_as_float(u & 0xffff0000u);
    }
    dst[(size_t)cls * DIM + tid*2]     = a0;
    dst[(size_t)cls * DIM + tid*2 + 1] = a1;
    if (mat == 0 && tid == 0) cnt[cls] = m;
}

// ---------------------------------------------------------------- fused GEMM
// S = scale*(img @ txt^T) once; epilogue accumulates ONLY exp sums.
// Double-buffered K-slices, ONE raw barrier per K-step, stage issued at step
// top and drained (vmcnt 0) at step bottom -> staging latency hidden under
// the step's ds_read+MFMA instead of exposed at a __syncthreads drain.
#define ASYNC16(gp, lp) \
  __builtin_amdgcn_global_load_lds((const __attribute__((address_space(1))) void*)(gp), \
                                   (__attribute__((address_space(3))) void*)(lp), 16, 0, 0)

#define SFENCE __builtin_amdgcn_sched_barrier(0)

#define STAGE(b, tcol, k0)                                                    \
  {                                                                           \
    const unsigned short* Ap = A + (size_t)(rowBase + w*16 + srow) * DIM      \
                                 + (k0) + spart;                              \
    const unsigned short* Bp = B + (size_t)((tcol) + w*16 + srow) * DIM       \
                                 + (k0) + spart;                              \
    ASYNC16(Ap,            &Ald[b][(w*16) * 32]);                             \
    ASYNC16(Ap + 64 * DIM, &Ald[b][(64 + w*16) * 32]);                        \
    ASYNC16(Bp,            &Bld[b][(w*16) * 32]);                             \
    ASYNC16(Bp + 64 * DIM, &Bld[b][(64 + w*16) * 32]);                        \
  }

#define STEP_SYNC                                                             \
  SFENCE;                                                                     \
  asm volatile("s_waitcnt vmcnt(0)" ::: "memory");                            \
  SFENCE;                                                                     \
  __builtin_amdgcn_s_barrier();                                               \
  SFENCE;

__global__ __launch_bounds__(256, 2) void gemm_fused_kernel(
    const unsigned short* __restrict__ imgn, const unsigned short* __restrict__ txtn,
    float* __restrict__ rs, float* __restrict__ cs)
{
    __shared__ unsigned short Ald[2][BM * 32];
    __shared__ unsigned short Bld[2][BN * 32];
    __shared__ float red[2][BM];
    __shared__ float colb[2][CHUNK];      // [wr][col-in-chunk], written once each

    // natural order: consecutive bids share a chunk -> B panel stays L2-hot,
    // A panels shared across XCDs while hot (round-1 FETCH behavior).
    int bid    = blockIdx.x;
    int rowblk = bid & 63;
    int chunk  = bid >> 6;
    const unsigned short* A = imgn;
    const unsigned short* B = txtn;
    int rowBase  = rowblk * BM;
    int colBase0 = chunk * CHUNK;

    int tid  = threadIdx.x;
    int lane = tid & 63;
    int w    = tid >> 6;
    int wr   = w >> 1, wc = w & 1;
    int q    = lane >> 4;
    int lm   = lane & 15;

    float s_acc[16];
    #pragma unroll
    for (int i = 0; i < 16; ++i) s_acc[i] = 0.f;

    int srow  = lane >> 2;        // staging: row within 16-row group
    int spart = (lane & 3) * 8;   // staging: k offset (elems)

    const float C1 = SCALE * LOG2E;
    const float C2 = -MAXLOGIT * LOG2E;

    // prologue: stage (tile0, k0) into buffer 0
    STAGE(0, colBase0, 0);
    STEP_SYNC;

    #pragma unroll 1
    for (int tile = 0; tile < CHUNK / BN; ++tile) {
        int colBase = colBase0 + tile * BN;
        f32x4 acc[4][4];
        #pragma unroll
        for (int mi = 0; mi < 4; ++mi)
          #pragma unroll
          for (int ni = 0; ni < 4; ++ni)
            acc[mi][ni] = (f32x4){0.f, 0.f, 0.f, 0.f};

        #pragma unroll
        for (int kt = 0; kt < DIM / 32; ++kt) {
            const int b = kt & 1;
            // prefetch next K-step (possibly next tile's k=0) into other buf
            if (kt < DIM / 32 - 1) {
                STAGE(b ^ 1, colBase, (kt + 1) * 32);
            } else if (tile < CHUNK / BN - 1) {
                STAGE(b ^ 1, colBase + BN, 0);
            }

            short8 af[4], bf[4];
            #pragma unroll
            for (int mi = 0; mi < 4; ++mi)
                af[mi] = *(const short8*)(&Ald[b][(wr*64 + mi*16 + lm)*32 + q*8]);
            #pragma unroll
            for (int ni = 0; ni < 4; ++ni)
                bf[ni] = *(const short8*)(&Bld[b][(wc*64 + ni*16 + lm)*32 + q*8]);
            #pragma unroll
            for (int mi = 0; mi < 4; ++mi)
              #pragma unroll
              for (int ni = 0; ni < 4; ++ni)
                acc[mi][ni] = __builtin_amdgcn_mfma_f32_16x16x32_bf16(
                                  af[mi], bf[ni], acc[mi][ni], 0, 0, 0);

            // epilogue on the tile's last K-step: exp-sum only; one exp
            // serves both loss directions. Runs before the step's vmcnt,
            // adding cover for the prefetch in flight.
            if (kt == DIM / 32 - 1) {
                #pragma unroll
                for (int ni = 0; ni < 4; ++ni) {
                    float csum = 0.f;
                    #pragma unroll
                    for (int mi = 0; mi < 4; ++mi) {
                      #pragma unroll
                      for (int r = 0; r < 4; ++r) {
                        float e = __builtin_amdgcn_exp2f(fmaf(acc[mi][ni][r], C1, C2));
                        s_acc[mi*4 + r] += e;
                        csum += e;
                      }
                    }
                    csum += __shfl_xor(csum, 16, 64);
                    csum += __shfl_xor(csum, 32, 64);
                    if (q == 0)
                        colb[wr][tile*BN + wc*64 + ni*16 + lm] = csum;
                }
            }
            STEP_SYNC;
        }
    }

    // row stats: reduce across the 16 column-lanes (low 4 lane bits)
    #pragma unroll
    for (int idx = 0; idx < 16; ++idx) {
        float s = s_acc[idx];
        #pragma unroll
        for (int m = 1; m < 16; m <<= 1) s += __shfl_xor(s, m, 64);
        s_acc[idx] = s;
    }
    if (lm == 0) {
        #pragma unroll
        for (int idx = 0; idx < 16; ++idx) {
            int rl = wr*64 + (idx>>2)*16 + q*4 + (idx&3);
            red[wc][rl] = s_acc[idx];
        }
    }
    __syncthreads();
    if (tid < BM)
        unsafeAtomicAdd(&rs[rowBase + tid], red[0][tid] + red[1][tid]);
    for (int c = tid; c < CHUNK; c += 256)
        unsafeAtomicAdd(&cs[colBase0 + c], colb[0][c] + colb[1][c]);
}

// ---------------------------------------------------------------- final loss
// loss*2N = Sum_i (M + log rs_i) + Sum_i (M + log cs_i)
//           - 2*scale*[ Sum_l <c_img[l],c_txt[l]>/cnt_l + Sum_{lab=-1} <a_i,b_i> ]
__global__ __launch_bounds__(256) void loss_tail_kernel(
    const float* __restrict__ rs, const float* __restrict__ cs,
    const float* __restrict__ sd, const float* __restrict__ c_txt,
    const float* __restrict__ c_img, const int* __restrict__ cnt,
    float* __restrict__ out)
{
    __shared__ float wsum[4];
    int tid = threadIdx.x, lane = tid & 63, w = tid >> 6;
    int gidx = blockIdx.x * 256 + tid;           // 0..16383
    float local;
    if (gidx < N_ROWS)
        local = (MAXLOGIT + logf(rs[gidx])) - 2.0f * SCALE * sd[gidx];
    else
        local = MAXLOGIT + logf(cs[gidx - N_ROWS]);

    // class-dot portion: 2 classes per block, 4 dims per thread
    int cls = blockIdx.x * 2 + (tid >> 7);       // 0..127
    int e0  = (tid & 127) * 4;
    int n   = cnt[cls];
    if (n > 0) {
        float4 x = *(const float4*)(c_txt + (size_t)cls * DIM + e0);
        float4 y = *(const float4*)(c_img + (size_t)cls * DIM + e0);
        float dotp = x.x*y.x + x.y*y.y + x.z*y.z + x.w*y.w;
        local -= 2.0f * SCALE * dotp / (float)n;
    }

    #pragma unroll
    for (int m = 1; m < 64; m <<= 1) local += __shfl_xor(local, m, 64);
    if (lane == 0) wsum[w] = local;
    __syncthreads();
    if (tid == 0)
        unsafeAtomicAdd(out, (wsum[0] + wsum[1] + wsum[2] + wsum[3])
                             * (1.0f / (2 * N_ROWS)));
}

// ---------------------------------------------------------------- launch
extern "C" void kernel_launch(void* const* d_in, const int* in_sizes, int n_in,
                              void* d_out, int out_size, void* d_ws, size_t ws_size,
                              hipStream_t stream)
{
    const float* text   = (const float*)d_in[0];
    const float* image  = (const float*)d_in[1];
    const int*   labels = (const int*)d_in[2];

    unsigned short* imgn = (unsigned short*)d_ws;
    unsigned short* txtn = imgn + (size_t)N_ROWS * DIM;
    char* p = (char*)d_ws + 2 * (size_t)N_ROWS * DIM * sizeof(unsigned short);
    float* rs    = (float*)p;                       // 8192 f32 (zeroed)
    float* cs    = rs + N_ROWS;                     // 8192 f32 (zeroed)
    float* sd    = cs + N_ROWS;                     // 8192 f32 (fully written)
    float* c_txt = sd + N_ROWS;                     // 128*512 f32
    float* c_img = c_txt + (size_t)NCLS * DIM;      // 128*512 f32
    int*   cnt   = (int*)(c_img + (size_t)NCLS * DIM);
    float* out = (float*)d_out;

    hipLaunchKernelGGL(norm_cast_kernel, dim3(N_ROWS / 4), dim3(256), 0, stream,
                       text, image, labels, imgn, txtn, (float4*)rs, sd, out);
    hipLaunchKernelGGL(gemm_fused_kernel, dim3(64 * NCHUNK), dim3(256), 0, stream,
                       imgn, txtn, rs, cs);
    hipLaunchKernelGGL(class_sum_kernel, dim3(2 * NCLS), dim3(256), 0, stream,
                       imgn, txtn, labels, c_txt, c_img, cnt);
    hipLaunchKernelGGL(loss_tail_kernel, dim3(64), dim3(256), 0, stream,
                       rs, cs, sd, c_txt, c_img, cnt, out);
}